// Round 7
// baseline (222.614 us; speedup 1.0000x reference)
//
#include <hip/hip_runtime.h>

#define EPS 1e-5f
#define LOG2E 1.4426950408889634f

typedef __attribute__((ext_vector_type(8)))  short    s8b;    // 8 bf16 (4 VGPR)
typedef __attribute__((ext_vector_type(4)))  short    s4b;    // 4 bf16 (b64)
typedef __attribute__((ext_vector_type(16))) float    f32x16; // 32x32 MFMA acc
typedef __attribute__((ext_vector_type(4)))  float    f32x4;
typedef __attribute__((ext_vector_type(4)))  unsigned u32x4;

__device__ __forceinline__ unsigned cvt_pk_bf16(float lo, float hi) {
    unsigned r;
    asm("v_cvt_pk_bf16_f32 %0, %1, %2" : "=v"(r) : "v"(lo), "v"(hi));
    return r;
}
__device__ __forceinline__ void permswap(unsigned &a, unsigned &b) {
    asm("v_permlane32_swap_b32 %0, %1" : "+v"(a), "+v"(b));
}
union PackAB { u32x4 u; s8b s; };

__device__ __forceinline__ unsigned short f2bf(float f) {
    union { float f; unsigned u; } v; v.f = f;
    unsigned r = v.u + 0x7FFFu + ((v.u >> 16) & 1u);
    return (unsigned short)(r >> 16);
}
__device__ __forceinline__ float bf2f(unsigned short h) {
    union { unsigned u; float f; } v; v.u = ((unsigned)h) << 16;
    return v.f;
}

// Fragment-major layouts (element indices, bf16):
//  Qf/Kf: ((((b*128 + ib)*4 + s)*2 + hi)*32 + l)*8 + e   i/j = ib*32+l, k = s*16+hi*8+e
//  Vf:    ((((b*128 + ib)*2 + s2)*2 + hi)*64 + c)*8 + e  k=i = ib*32+s2*16+hi*8+e, col=c
// Q is pre-scaled by LOG2E so exp(S) == exp2(S').

// ---------------------------------------------------------------------------
// Kernel A (MFMA): fused 1x1-conv + BN (+ mask, +LOG2E for Q), bf16-split W
// block = (b, 64-wide p strip); 4 waves = phalf(2) x ohalf(2)
// ---------------------------------------------------------------------------
__global__ __launch_bounds__(256) void qkv_kernel(
    const float* __restrict__ x, const float* __restrict__ sal,
    const float* __restrict__ wq, const float* __restrict__ bq,
    const float* __restrict__ gq, const float* __restrict__ beq,
    const float* __restrict__ wk, const float* __restrict__ bk,
    const float* __restrict__ gk, const float* __restrict__ bek,
    const float* __restrict__ wv, const float* __restrict__ bv,
    const float* __restrict__ gv, const float* __restrict__ bev,
    short* __restrict__ Qf, short* __restrict__ Kf, short* __restrict__ Vf)
{
    __shared__ short wbf[6][4096];    // [m*2+hl][(o*64+c) ^ ((o&7)<<3)]
    __shared__ short xbf[4096];       // [(p*64+c) ^ ((p&7)<<3)]
    __shared__ short v_lds[4096];     // [(c*64+p) ^ ((c&7)<<3)]
    __shared__ float sc_lds[3][64];
    __shared__ float bb_lds[3][64];

    const int t = threadIdx.x;
    const int b = blockIdx.x & 7;
    const int p0 = (blockIdx.x >> 3) * 64;

    if (t < 192) {
        int m = t >> 6, o = t & 63;
        const float* g  = (m == 0) ? gq  : (m == 1) ? gk  : gv;
        const float* be = (m == 0) ? beq : (m == 1) ? bek : bev;
        const float* bi = (m == 0) ? bq  : (m == 1) ? bk  : bv;
        float lam = (m == 0) ? LOG2E : 1.0f;
        float s = g[o] * rsqrtf(1.0f + EPS) * lam;
        sc_lds[m][o] = s;
        bb_lds[m][o] = bi[o] * s + be[o] * lam;
    }
    __syncthreads();

    // stage W -> scaled bf16 hi/lo split
    for (int rep = 0; rep < 12; ++rep) {
        int idx = (rep * 256 + t) * 4;
        int m = idx >> 12;
        int r = idx & 4095;
        int o = r >> 6, c0 = r & 63;
        const float* w = (m == 0) ? wq : (m == 1) ? wk : wv;
        float4 v4 = *reinterpret_cast<const float4*>(w + r);
        float s = sc_lds[m][o];
        float w0 = v4.x * s, w1 = v4.y * s, w2 = v4.z * s, w3 = v4.w * s;
        unsigned short h0 = f2bf(w0), h1 = f2bf(w1), h2 = f2bf(w2), h3 = f2bf(w3);
        s4b hv, lv;
        hv[0] = (short)h0; hv[1] = (short)h1; hv[2] = (short)h2; hv[3] = (short)h3;
        lv[0] = (short)f2bf(w0 - bf2f(h0));
        lv[1] = (short)f2bf(w1 - bf2f(h1));
        lv[2] = (short)f2bf(w2 - bf2f(h2));
        lv[3] = (short)f2bf(w3 - bf2f(h3));
        int sidx = (o * 64 + c0) ^ ((o & 7) << 3);
        *reinterpret_cast<s4b*>(&wbf[m * 2 + 0][sidx]) = hv;
        *reinterpret_cast<s4b*>(&wbf[m * 2 + 1][sidx]) = lv;
    }
    // stage x -> bf16, transposed [p][c]
    {
        const int xp = t & 63;
        const int cgrp = (t >> 6) * 4;
        const float* xb = x + ((size_t)(b * 64) << 12) + p0 + xp;
        for (int rep = 0; rep < 4; ++rep) {
            int cb = cgrp + rep * 16;
            float x0 = xb[(size_t)(cb + 0) << 12];
            float x1 = xb[(size_t)(cb + 1) << 12];
            float x2 = xb[(size_t)(cb + 2) << 12];
            float x3 = xb[(size_t)(cb + 3) << 12];
            s4b pk;
            pk[0] = (short)f2bf(x0); pk[1] = (short)f2bf(x1);
            pk[2] = (short)f2bf(x2); pk[3] = (short)f2bf(x3);
            int sidx = (xp * 64 + cb) ^ ((xp & 7) << 3);
            *reinterpret_cast<s4b*>(&xbf[sidx]) = pk;
        }
    }
    __syncthreads();

    const int lane = t & 63, wave = t >> 6;
    const int l31 = lane & 31, hi = lane >> 5;
    const int phalf = wave & 1, ohalf = wave >> 1;
    const int prow = phalf * 32 + l31;
    const int orow = ohalf * 32 + l31;
    const int ib = (p0 >> 5) + phalf;
    const int swz = (l31 & 7) << 3;

    s8b bx[4];
#pragma unroll
    for (int s = 0; s < 4; ++s)
        bx[s] = *reinterpret_cast<const s8b*>(
            &xbf[(prow * 64 + s * 16 + hi * 8) ^ ((prow & 7) << 3)]);

    const float msk = sal[(((size_t)b) << 12) + p0 + prow];

#pragma unroll
    for (int m = 0; m < 3; ++m) {
        s8b ah[4], al[4];
#pragma unroll
        for (int s = 0; s < 4; ++s) {
            int sidx = (orow * 64 + s * 16 + hi * 8) ^ swz;
            ah[s] = *reinterpret_cast<const s8b*>(&wbf[m * 2 + 0][sidx]);
            al[s] = *reinterpret_cast<const s8b*>(&wbf[m * 2 + 1][sidx]);
        }
        f32x16 d;
#pragma unroll
        for (int r = 0; r < 16; ++r) d[r] = 0.f;
#pragma unroll
        for (int s = 0; s < 4; ++s)
            d = __builtin_amdgcn_mfma_f32_32x32x16_bf16(ah[s], bx[s], d, 0, 0, 0);
#pragma unroll
        for (int s = 0; s < 4; ++s)
            d = __builtin_amdgcn_mfma_f32_32x32x16_bf16(al[s], bx[s], d, 0, 0, 0);

        float pv[16];
#pragma unroll
        for (int g = 0; g < 4; ++g) {
            f32x4 bb = *reinterpret_cast<const f32x4*>(
                &bb_lds[m][ohalf * 32 + 8 * g + 4 * hi]);
#pragma unroll
            for (int q = 0; q < 4; ++q) pv[g * 4 + q] = d[g * 4 + q] + bb[q];
        }
        if (m == 0) {
#pragma unroll
            for (int r = 0; r < 16; ++r) pv[r] *= msk;
        }
        if (m < 2) {
            unsigned a0 = cvt_pk_bf16(pv[0],  pv[1]);
            unsigned a1 = cvt_pk_bf16(pv[2],  pv[3]);
            unsigned a2 = cvt_pk_bf16(pv[4],  pv[5]);
            unsigned a3 = cvt_pk_bf16(pv[6],  pv[7]);
            unsigned b0 = cvt_pk_bf16(pv[8],  pv[9]);
            unsigned b1 = cvt_pk_bf16(pv[10], pv[11]);
            unsigned b2 = cvt_pk_bf16(pv[12], pv[13]);
            unsigned b3 = cvt_pk_bf16(pv[14], pv[15]);
            permswap(a0, a2); permswap(a1, a3);
            permswap(b0, b2); permswap(b1, b3);
            PackAB pa0, pa1;
            pa0.u.x = a0; pa0.u.y = a1; pa0.u.z = a2; pa0.u.w = a3;
            pa1.u.x = b0; pa1.u.y = b1; pa1.u.z = b2; pa1.u.w = b3;
            short* dst = (m == 0) ? Qf : Kf;
            size_t base =
                ((((size_t)(b * 128 + ib) * 4 + ohalf * 2) * 2 + hi) * 32 + l31) * 8;
            *reinterpret_cast<u32x4*>(dst + base)       = pa0.u;
            *reinterpret_cast<u32x4*>(dst + base + 512) = pa1.u;  // s+1
        } else {
#pragma unroll
            for (int r = 0; r < 16; ++r) {
                int c = ohalf * 32 + (r & 3) + 8 * (r >> 2) + 4 * hi;
                int sidx = (c * 64 + prow) ^ ((c & 7) << 3);
                v_lds[sidx] = (short)f2bf(pv[r]);
            }
        }
    }
    __syncthreads();

    // cooperative Vf write (fragment-major, contiguous)
    const size_t vbase = (size_t)(b * 128 + (p0 >> 5)) * 2048;
#pragma unroll
    for (int r = 0; r < 2; ++r) {
        int f = r * 256 + t;
        int c = f & 63;
        int iL = ((f >> 6) & 7) * 8;
        int sidx = (c * 64 + iL) ^ ((c & 7) << 3);
        u32x4 val = *reinterpret_cast<const u32x4*>(&v_lds[sidx]);
        *reinterpret_cast<u32x4*>(Vf + vbase + (size_t)f * 8) = val;
    }
}

// ---------------------------------------------------------------------------
// Kernel B (MFMA): inv_l[b][i] = 1 / sum_j exp2(S'[i][j]); kf prefetched
// ---------------------------------------------------------------------------
#define LOADK(JB, DST) {                                                      \
    const short* _kp = Kf +                                                   \
        ((((size_t)(b * 128 + (JB)) * 4) * 2 + hi) * 32 + l31) * 8;           \
    DST[0] = *reinterpret_cast<const s8b*>(_kp);                              \
    DST[1] = *reinterpret_cast<const s8b*>(_kp + 512);                        \
    DST[2] = *reinterpret_cast<const s8b*>(_kp + 1024);                       \
    DST[3] = *reinterpret_cast<const s8b*>(_kp + 1536); }

#define RBODY(KARR) {                                                         \
    f32x16 sacc;                                                              \
    _Pragma("unroll") for (int r = 0; r < 16; ++r) sacc[r] = 0.f;             \
    __builtin_amdgcn_s_setprio(1);                                            \
    _Pragma("unroll") for (int s = 0; s < 4; ++s)                             \
        sacc = __builtin_amdgcn_mfma_f32_32x32x16_bf16(qf[s], KARR[s], sacc, 0, 0, 0); \
    __builtin_amdgcn_s_setprio(0);                                            \
    _Pragma("unroll") for (int r = 0; r < 16; ++r)                            \
        lsum[r] += __builtin_exp2f(sacc[r]); }

__global__ __launch_bounds__(256, 4) void rowsum_kernel(
    const short* __restrict__ Qf, const short* __restrict__ Kf,
    float* __restrict__ inv_l)
{
    __shared__ float part[4][32];

    const int t = threadIdx.x;
    const int b = blockIdx.x & 7;
    const int it = blockIdx.x >> 3;          // i-block 0..127
    const int wave = t >> 6, lane = t & 63;
    const int l31 = lane & 31, hi = lane >> 5;

    const short* qp = Qf +
        ((((size_t)(b * 128 + it) * 4) * 2 + hi) * 32 + l31) * 8;
    s8b qf[4];
#pragma unroll
    for (int s = 0; s < 4; ++s)
        qf[s] = *reinterpret_cast<const s8b*>(qp + s * 512);

    float lsum[16];
#pragma unroll
    for (int r = 0; r < 16; ++r) lsum[r] = 0.f;

    s8b kA[4], kB[4];
    LOADK(wave, kA);
    for (int ii = 0; ii < 32; ii += 2) {
        LOADK(wave + (ii + 1) * 4, kB);
        RBODY(kA);
        if (ii + 2 < 32) { LOADK(wave + (ii + 2) * 4, kA); }
        RBODY(kB);
    }

#pragma unroll
    for (int off = 1; off < 32; off <<= 1)
#pragma unroll
        for (int r = 0; r < 16; ++r) lsum[r] += __shfl_xor(lsum[r], off);

    if (l31 == 0) {
#pragma unroll
        for (int r = 0; r < 16; ++r) {
            int iloc = (r & 3) + 8 * (r >> 2) + 4 * hi;
            part[wave][iloc] = lsum[r];
        }
    }
    __syncthreads();
    if (t < 32)
        inv_l[(((size_t)b) << 12) + it * 32 + t] =
            1.0f / (part[0][t] + part[1][t] + part[2][t] + part[3][t]);
}

// ---------------------------------------------------------------------------
// Kernel C (MFMA): out = BN_o( V @ softmax + x )
// block = (b, 32-col j-block); 4 waves wr = i-split; qf double-buffered.
// ---------------------------------------------------------------------------
#define LOADQ(IB, DST) {                                                      \
    const short* _qp = Qf +                                                   \
        ((((size_t)(b * 128 + (IB)) * 4) * 2 + hi) * 32 + l31) * 8;           \
    DST[0] = *reinterpret_cast<const s8b*>(_qp);                              \
    DST[1] = *reinterpret_cast<const s8b*>(_qp + 512);                        \
    DST[2] = *reinterpret_cast<const s8b*>(_qp + 1024);                       \
    DST[3] = *reinterpret_cast<const s8b*>(_qp + 1536); }

#define LOADV(IB) {                                                           \
    const short* _vp = Vf +                                                   \
        ((((size_t)(b * 128 + (IB)) * 2) * 2 + hi) * 64 + l31) * 8;           \
    vf[0] = *reinterpret_cast<const s8b*>(_vp);                               \
    vf[1] = *reinterpret_cast<const s8b*>(_vp + 256);                         \
    vf[2] = *reinterpret_cast<const s8b*>(_vp + 1024);                        \
    vf[3] = *reinterpret_cast<const s8b*>(_vp + 1280); }

#define ABODY(QARR, IB) {                                                     \
    f32x16 sacc;                                                              \
    _Pragma("unroll") for (int r = 0; r < 16; ++r) sacc[r] = 0.f;             \
    __builtin_amdgcn_s_setprio(1);                                            \
    _Pragma("unroll") for (int s = 0; s < 4; ++s)                             \
        sacc = __builtin_amdgcn_mfma_f32_32x32x16_bf16(QARR[s], kf[s], sacc, 0, 0, 0); \
    __builtin_amdgcn_s_setprio(0);                                            \
    float p[16];                                                              \
    const int _ibase = (IB) * 32 + 4 * hi;                                    \
    _Pragma("unroll") for (int g = 0; g < 4; ++g) {                           \
        f32x4 li = *reinterpret_cast<const f32x4*>(lip + _ibase + 8 * g);     \
        _Pragma("unroll") for (int q = 0; q < 4; ++q)                         \
            p[g * 4 + q] = __builtin_exp2f(sacc[g * 4 + q]) * li[q];          \
    }                                                                         \
    unsigned a0 = cvt_pk_bf16(p[0],  p[1]),  a1 = cvt_pk_bf16(p[2],  p[3]);   \
    unsigned a2 = cvt_pk_bf16(p[4],  p[5]),  a3 = cvt_pk_bf16(p[6],  p[7]);   \
    unsigned b0 = cvt_pk_bf16(p[8],  p[9]),  b1 = cvt_pk_bf16(p[10], p[11]);  \
    unsigned b2 = cvt_pk_bf16(p[12], p[13]), b3 = cvt_pk_bf16(p[14], p[15]);  \
    permswap(a0, a2); permswap(a1, a3); permswap(b0, b2); permswap(b1, b3);   \
    PackAB pa0, pa1;                                                          \
    pa0.u.x = a0; pa0.u.y = a1; pa0.u.z = a2; pa0.u.w = a3;                   \
    pa1.u.x = b0; pa1.u.y = b1; pa1.u.z = b2; pa1.u.w = b3;                   \
    __builtin_amdgcn_s_setprio(1);                                            \
    acc0 = __builtin_amdgcn_mfma_f32_32x32x16_bf16(pa0.s, vf[0], acc0, 0, 0, 0); \
    acc1 = __builtin_amdgcn_mfma_f32_32x32x16_bf16(pa0.s, vf[1], acc1, 0, 0, 0); \
    acc0 = __builtin_amdgcn_mfma_f32_32x32x16_bf16(pa1.s, vf[2], acc0, 0, 0, 0); \
    acc1 = __builtin_amdgcn_mfma_f32_32x32x16_bf16(pa1.s, vf[3], acc1, 0, 0, 0); \
    __builtin_amdgcn_s_setprio(0); }

__global__ __launch_bounds__(256, 4) void attnout_kernel(
    const short* __restrict__ Qf, const short* __restrict__ Kf,
    const short* __restrict__ Vf, const float* __restrict__ inv_l,
    const float* __restrict__ x, const float* __restrict__ go,
    const float* __restrict__ beo, float* __restrict__ out)
{
    __shared__ float red[3][64][33];       // wr=1..3 partials

    const int t = threadIdx.x;
    const int b = blockIdx.x & 7;
    const int jb = blockIdx.x >> 3;        // j-block 0..127
    const int wave = t >> 6, lane = t & 63;
    const int wr = wave;                   // i-split 0..3
    const int l31 = lane & 31, hi = lane >> 5;

    const short* kp = Kf +
        ((((size_t)(b * 128 + jb) * 4) * 2 + hi) * 32 + l31) * 8;
    s8b kf[4];
#pragma unroll
    for (int s = 0; s < 4; ++s)
        kf[s] = *reinterpret_cast<const s8b*>(kp + s * 512);

    f32x16 acc0, acc1;
#pragma unroll
    for (int r = 0; r < 16; ++r) { acc0[r] = 0.f; acc1[r] = 0.f; }

    const float* lip = inv_l + (((size_t)b) << 12);

    s8b qA[4], qB[4], vf[4];
    LOADQ(wr, qA);
    LOADV(wr);
    for (int ii = 0; ii < 32; ii += 2) {
        const int ibA = ii * 4 + wr;
        const int ibB = ibA + 4;
        LOADQ(ibB, qB);
        ABODY(qA, ibA);
        LOADV(ibB);
        if (ii + 2 < 32) { LOADQ(ibA + 8, qA); }
        ABODY(qB, ibB);
        if (ii + 2 < 32) { LOADV(ibA + 8); }
    }

    if (wr > 0) {
#pragma unroll
        for (int nf = 0; nf < 2; ++nf) {
            const f32x16& A = nf ? acc1 : acc0;
            int c = nf * 32 + l31;
#pragma unroll
            for (int g = 0; g < 4; ++g) {
                f32x4 v;
                v.x = A[g * 4 + 0]; v.y = A[g * 4 + 1];
                v.z = A[g * 4 + 2]; v.w = A[g * 4 + 3];
                *reinterpret_cast<f32x4*>(&red[wr - 1][c][g * 8 + 4 * hi]) = v;
            }
        }
    }
    __syncthreads();
    if (wr == 0) {
#pragma unroll
        for (int nf = 0; nf < 2; ++nf) {
            const f32x16& A = nf ? acc1 : acc0;
            int c = nf * 32 + l31;
            const float sc = go[c] * rsqrtf(1.0f + EPS);
            const float bb = beo[c];
            size_t rowb = (((size_t)(b * 64 + c)) << 12) + jb * 32;
#pragma unroll
            for (int g = 0; g < 4; ++g) {
                int jl = g * 8 + 4 * hi;
                f32x4 p0 = *reinterpret_cast<const f32x4*>(&red[0][c][jl]);
                f32x4 p1 = *reinterpret_cast<const f32x4*>(&red[1][c][jl]);
                f32x4 p2 = *reinterpret_cast<const f32x4*>(&red[2][c][jl]);
                f32x4 xv = *reinterpret_cast<const f32x4*>(x + rowb + jl);
                f32x4 ov;
                ov.x = (A[g * 4 + 0] + p0.x + p1.x + p2.x + xv.x) * sc + bb;
                ov.y = (A[g * 4 + 1] + p0.y + p1.y + p2.y + xv.y) * sc + bb;
                ov.z = (A[g * 4 + 2] + p0.z + p1.z + p2.z + xv.z) * sc + bb;
                ov.w = (A[g * 4 + 3] + p0.w + p1.w + p2.w + xv.w) * sc + bb;
                *reinterpret_cast<f32x4*>(out + rowb + jl) = ov;
            }
        }
    }
}

extern "C" void kernel_launch(void* const* d_in, const int* in_sizes, int n_in,
                              void* d_out, int out_size, void* d_ws, size_t ws_size,
                              hipStream_t stream)
{
    (void)in_sizes; (void)n_in; (void)out_size; (void)ws_size;
    const float* x   = (const float*)d_in[0];
    const float* sal = (const float*)d_in[1];
    const float* wq  = (const float*)d_in[2];  const float* bq  = (const float*)d_in[3];
    const float* gq  = (const float*)d_in[4];  const float* beq = (const float*)d_in[5];
    const float* wk  = (const float*)d_in[6];  const float* bk  = (const float*)d_in[7];
    const float* gk  = (const float*)d_in[8];  const float* bek = (const float*)d_in[9];
    const float* wv  = (const float*)d_in[10]; const float* bv  = (const float*)d_in[11];
    const float* gv  = (const float*)d_in[12]; const float* bev = (const float*)d_in[13];
    const float* go  = (const float*)d_in[14]; const float* beo = (const float*)d_in[15];
    float* out = (float*)d_out;

    short* ws = (short*)d_ws;
    short* Qf = ws;                     // 2,097,152 bf16
    short* Kf = ws + 2097152;           // 2,097,152 bf16
    short* Vf = ws + 4194304;           // 2,097,152 bf16
    float* il = (float*)(ws + 6291456); // 32,768 f32

    qkv_kernel<<<512, 256, 0, stream>>>(x, sal, wq, bq, gq, beq,
                                        wk, bk, gk, bek, wv, bv, gv, bev,
                                        Qf, Kf, Vf);
    rowsum_kernel<<<1024, 256, 0, stream>>>(Qf, Kf, il);
    attnout_kernel<<<1024, 256, 0, stream>>>(Qf, Kf, Vf, il, x, go, beo, out);
}

// Round 8
// 199.887 us; speedup vs baseline: 1.1137x; 1.1137x over previous
//
#include <hip/hip_runtime.h>

#define EPS 1e-5f
#define LOG2E 1.4426950408889634f

typedef __attribute__((ext_vector_type(8)))  short    s8b;    // 8 bf16 (4 VGPR)
typedef __attribute__((ext_vector_type(4)))  short    s4b;    // 4 bf16 (b64)
typedef __attribute__((ext_vector_type(16))) float    f32x16; // 32x32 MFMA acc
typedef __attribute__((ext_vector_type(4)))  float    f32x4;
typedef __attribute__((ext_vector_type(4)))  unsigned u32x4;

__device__ __forceinline__ unsigned cvt_pk_bf16(float lo, float hi) {
    unsigned r;
    asm("v_cvt_pk_bf16_f32 %0, %1, %2" : "=v"(r) : "v"(lo), "v"(hi));
    return r;
}
__device__ __forceinline__ void permswap(unsigned &a, unsigned &b) {
    asm("v_permlane32_swap_b32 %0, %1" : "+v"(a), "+v"(b));
}
union PackAB { u32x4 u; s8b s; };

__device__ __forceinline__ unsigned short f2bf(float f) {
    union { float f; unsigned u; } v; v.f = f;
    unsigned r = v.u + 0x7FFFu + ((v.u >> 16) & 1u);
    return (unsigned short)(r >> 16);
}
__device__ __forceinline__ float bf2f(unsigned short h) {
    union { unsigned u; float f; } v; v.u = ((unsigned)h) << 16;
    return v.f;
}

// Fragment-major layouts (element indices, bf16):
//  Qf/Kf: ((((b*128 + ib)*4 + s)*2 + hi)*32 + l)*8 + e   i/j = ib*32+l, k = s*16+hi*8+e
//  Vf:    ((((b*128 + ib)*2 + s2)*2 + hi)*64 + c)*8 + e  k=i = ib*32+s2*16+hi*8+e, col=c
// Q is pre-scaled by LOG2E so exp(S) == exp2(S').

// ---------------------------------------------------------------------------
// Kernel A (MFMA): fused 1x1-conv + BN (+ mask, +LOG2E for Q), bf16-split W
// block = (b, 64-wide p strip); 4 waves = phalf(2) x ohalf(2)
// ---------------------------------------------------------------------------
__global__ __launch_bounds__(256) void qkv_kernel(
    const float* __restrict__ x, const float* __restrict__ sal,
    const float* __restrict__ wq, const float* __restrict__ bq,
    const float* __restrict__ gq, const float* __restrict__ beq,
    const float* __restrict__ wk, const float* __restrict__ bk,
    const float* __restrict__ gk, const float* __restrict__ bek,
    const float* __restrict__ wv, const float* __restrict__ bv,
    const float* __restrict__ gv, const float* __restrict__ bev,
    short* __restrict__ Qf, short* __restrict__ Kf, short* __restrict__ Vf)
{
    __shared__ short wbf[6][4096];    // [m*2+hl][(o*64+c) ^ ((o&7)<<3)]
    __shared__ short xbf[4096];       // [(p*64+c) ^ ((p&7)<<3)]
    __shared__ short v_lds[4096];     // [(c*64+p) ^ ((c&7)<<3)]
    __shared__ float sc_lds[3][64];
    __shared__ float bb_lds[3][64];

    const int t = threadIdx.x;
    const int b = blockIdx.x & 7;
    const int p0 = (blockIdx.x >> 3) * 64;

    if (t < 192) {
        int m = t >> 6, o = t & 63;
        const float* g  = (m == 0) ? gq  : (m == 1) ? gk  : gv;
        const float* be = (m == 0) ? beq : (m == 1) ? bek : bev;
        const float* bi = (m == 0) ? bq  : (m == 1) ? bk  : bv;
        float lam = (m == 0) ? LOG2E : 1.0f;
        float s = g[o] * rsqrtf(1.0f + EPS) * lam;
        sc_lds[m][o] = s;
        bb_lds[m][o] = bi[o] * s + be[o] * lam;
    }
    __syncthreads();

    // stage W -> scaled bf16 hi/lo split
    for (int rep = 0; rep < 12; ++rep) {
        int idx = (rep * 256 + t) * 4;
        int m = idx >> 12;
        int r = idx & 4095;
        int o = r >> 6, c0 = r & 63;
        const float* w = (m == 0) ? wq : (m == 1) ? wk : wv;
        float4 v4 = *reinterpret_cast<const float4*>(w + r);
        float s = sc_lds[m][o];
        float w0 = v4.x * s, w1 = v4.y * s, w2 = v4.z * s, w3 = v4.w * s;
        unsigned short h0 = f2bf(w0), h1 = f2bf(w1), h2 = f2bf(w2), h3 = f2bf(w3);
        s4b hv, lv;
        hv[0] = (short)h0; hv[1] = (short)h1; hv[2] = (short)h2; hv[3] = (short)h3;
        lv[0] = (short)f2bf(w0 - bf2f(h0));
        lv[1] = (short)f2bf(w1 - bf2f(h1));
        lv[2] = (short)f2bf(w2 - bf2f(h2));
        lv[3] = (short)f2bf(w3 - bf2f(h3));
        int sidx = (o * 64 + c0) ^ ((o & 7) << 3);
        *reinterpret_cast<s4b*>(&wbf[m * 2 + 0][sidx]) = hv;
        *reinterpret_cast<s4b*>(&wbf[m * 2 + 1][sidx]) = lv;
    }
    // stage x -> bf16, transposed [p][c]
    {
        const int xp = t & 63;
        const int cgrp = (t >> 6) * 4;
        const float* xb = x + ((size_t)(b * 64) << 12) + p0 + xp;
        for (int rep = 0; rep < 4; ++rep) {
            int cb = cgrp + rep * 16;
            float x0 = xb[(size_t)(cb + 0) << 12];
            float x1 = xb[(size_t)(cb + 1) << 12];
            float x2 = xb[(size_t)(cb + 2) << 12];
            float x3 = xb[(size_t)(cb + 3) << 12];
            s4b pk;
            pk[0] = (short)f2bf(x0); pk[1] = (short)f2bf(x1);
            pk[2] = (short)f2bf(x2); pk[3] = (short)f2bf(x3);
            int sidx = (xp * 64 + cb) ^ ((xp & 7) << 3);
            *reinterpret_cast<s4b*>(&xbf[sidx]) = pk;
        }
    }
    __syncthreads();

    const int lane = t & 63, wave = t >> 6;
    const int l31 = lane & 31, hi = lane >> 5;
    const int phalf = wave & 1, ohalf = wave >> 1;
    const int prow = phalf * 32 + l31;
    const int orow = ohalf * 32 + l31;
    const int ib = (p0 >> 5) + phalf;
    const int swz = (l31 & 7) << 3;

    s8b bx[4];
#pragma unroll
    for (int s = 0; s < 4; ++s)
        bx[s] = *reinterpret_cast<const s8b*>(
            &xbf[(prow * 64 + s * 16 + hi * 8) ^ ((prow & 7) << 3)]);

    const float msk = sal[(((size_t)b) << 12) + p0 + prow];

#pragma unroll
    for (int m = 0; m < 3; ++m) {
        s8b ah[4], al[4];
#pragma unroll
        for (int s = 0; s < 4; ++s) {
            int sidx = (orow * 64 + s * 16 + hi * 8) ^ swz;
            ah[s] = *reinterpret_cast<const s8b*>(&wbf[m * 2 + 0][sidx]);
            al[s] = *reinterpret_cast<const s8b*>(&wbf[m * 2 + 1][sidx]);
        }
        f32x16 d;
#pragma unroll
        for (int r = 0; r < 16; ++r) d[r] = 0.f;
#pragma unroll
        for (int s = 0; s < 4; ++s)
            d = __builtin_amdgcn_mfma_f32_32x32x16_bf16(ah[s], bx[s], d, 0, 0, 0);
#pragma unroll
        for (int s = 0; s < 4; ++s)
            d = __builtin_amdgcn_mfma_f32_32x32x16_bf16(al[s], bx[s], d, 0, 0, 0);

        float pv[16];
#pragma unroll
        for (int g = 0; g < 4; ++g) {
            f32x4 bb = *reinterpret_cast<const f32x4*>(
                &bb_lds[m][ohalf * 32 + 8 * g + 4 * hi]);
#pragma unroll
            for (int q = 0; q < 4; ++q) pv[g * 4 + q] = d[g * 4 + q] + bb[q];
        }
        if (m == 0) {
#pragma unroll
            for (int r = 0; r < 16; ++r) pv[r] *= msk;
        }
        if (m < 2) {
            unsigned a0 = cvt_pk_bf16(pv[0],  pv[1]);
            unsigned a1 = cvt_pk_bf16(pv[2],  pv[3]);
            unsigned a2 = cvt_pk_bf16(pv[4],  pv[5]);
            unsigned a3 = cvt_pk_bf16(pv[6],  pv[7]);
            unsigned b0 = cvt_pk_bf16(pv[8],  pv[9]);
            unsigned b1 = cvt_pk_bf16(pv[10], pv[11]);
            unsigned b2 = cvt_pk_bf16(pv[12], pv[13]);
            unsigned b3 = cvt_pk_bf16(pv[14], pv[15]);
            permswap(a0, a2); permswap(a1, a3);
            permswap(b0, b2); permswap(b1, b3);
            PackAB pa0, pa1;
            pa0.u.x = a0; pa0.u.y = a1; pa0.u.z = a2; pa0.u.w = a3;
            pa1.u.x = b0; pa1.u.y = b1; pa1.u.z = b2; pa1.u.w = b3;
            short* dst = (m == 0) ? Qf : Kf;
            size_t base =
                ((((size_t)(b * 128 + ib) * 4 + ohalf * 2) * 2 + hi) * 32 + l31) * 8;
            *reinterpret_cast<u32x4*>(dst + base)       = pa0.u;
            *reinterpret_cast<u32x4*>(dst + base + 512) = pa1.u;  // s+1
        } else {
#pragma unroll
            for (int r = 0; r < 16; ++r) {
                int c = ohalf * 32 + (r & 3) + 8 * (r >> 2) + 4 * hi;
                int sidx = (c * 64 + prow) ^ ((c & 7) << 3);
                v_lds[sidx] = (short)f2bf(pv[r]);
            }
        }
    }
    __syncthreads();

    // cooperative Vf write (fragment-major, contiguous)
    const size_t vbase = (size_t)(b * 128 + (p0 >> 5)) * 2048;
#pragma unroll
    for (int r = 0; r < 2; ++r) {
        int f = r * 256 + t;
        int c = f & 63;
        int iL = ((f >> 6) & 7) * 8;
        int sidx = (c * 64 + iL) ^ ((c & 7) << 3);
        u32x4 val = *reinterpret_cast<const u32x4*>(&v_lds[sidx]);
        *reinterpret_cast<u32x4*>(Vf + vbase + (size_t)f * 8) = val;
    }
}

// ---------------------------------------------------------------------------
// Kernel B (MFMA): inv_l[b][i] = 1 / sum_j exp2(S'[i][j])
// block = (b, 64-row i-tile); 8 waves = wi(2 i-blocks) x wj(4-way j-split);
// kf double-buffered.
// ---------------------------------------------------------------------------
#define LOADK(JB, DST) {                                                      \
    const short* _kp = Kf +                                                   \
        ((((size_t)(b * 128 + (JB)) * 4) * 2 + hi) * 32 + l31) * 8;           \
    DST[0] = *reinterpret_cast<const s8b*>(_kp);                              \
    DST[1] = *reinterpret_cast<const s8b*>(_kp + 512);                        \
    DST[2] = *reinterpret_cast<const s8b*>(_kp + 1024);                       \
    DST[3] = *reinterpret_cast<const s8b*>(_kp + 1536); }

#define RBODY(KARR) {                                                         \
    f32x16 sacc;                                                              \
    _Pragma("unroll") for (int r = 0; r < 16; ++r) sacc[r] = 0.f;             \
    __builtin_amdgcn_s_setprio(1);                                            \
    _Pragma("unroll") for (int s = 0; s < 4; ++s)                             \
        sacc = __builtin_amdgcn_mfma_f32_32x32x16_bf16(qf[s], KARR[s], sacc, 0, 0, 0); \
    __builtin_amdgcn_s_setprio(0);                                            \
    _Pragma("unroll") for (int r = 0; r < 16; ++r)                            \
        lsum[r] += __builtin_exp2f(sacc[r]); }

__global__ __launch_bounds__(512, 2) void rowsum_kernel(
    const short* __restrict__ Qf, const short* __restrict__ Kf,
    float* __restrict__ inv_l)
{
    __shared__ float part[8][32];

    const int t = threadIdx.x;
    const int b = blockIdx.x & 7;
    const int it2 = blockIdx.x >> 3;         // i-tile 0..63 (64 rows each)
    const int wave = t >> 6, lane = t & 63;
    const int wi = wave & 1, wj = wave >> 1; // i-block within tile, j-split
    const int l31 = lane & 31, hi = lane >> 5;

    const short* qp = Qf +
        ((((size_t)(b * 128 + it2 * 2 + wi) * 4) * 2 + hi) * 32 + l31) * 8;
    s8b qf[4];
#pragma unroll
    for (int s = 0; s < 4; ++s)
        qf[s] = *reinterpret_cast<const s8b*>(qp + s * 512);

    float lsum[16];
#pragma unroll
    for (int r = 0; r < 16; ++r) lsum[r] = 0.f;

    s8b kA[4], kB[4];
    LOADK(wj, kA);
    for (int jj = 0; jj < 32; jj += 2) {
        LOADK((jj + 1) * 4 + wj, kB);
        RBODY(kA);
        if (jj + 2 < 32) { LOADK((jj + 2) * 4 + wj, kA); }
        RBODY(kB);
    }

#pragma unroll
    for (int off = 1; off < 32; off <<= 1)
#pragma unroll
        for (int r = 0; r < 16; ++r) lsum[r] += __shfl_xor(lsum[r], off);

    if (l31 == 0) {
#pragma unroll
        for (int r = 0; r < 16; ++r) {
            int iloc = (r & 3) + 8 * (r >> 2) + 4 * hi;
            part[wave][iloc] = lsum[r];
        }
    }
    __syncthreads();
    if (t < 64) {
        int wi_t = t >> 5, row = t & 31;
        float s = part[wi_t][row] + part[2 + wi_t][row] +
                  part[4 + wi_t][row] + part[6 + wi_t][row];
        inv_l[(((size_t)b) << 12) + it2 * 64 + wi_t * 32 + row] = 1.0f / s;
    }
}

// ---------------------------------------------------------------------------
// Kernel C (MFMA): out = BN_o( V @ softmax + x )
// block = (b, 64-col j-tile); 8 waves = wr(4-way i-split) x wc(2 j-halves).
// q AND v double-buffered; one full ABODY of latency cover per load.
// ---------------------------------------------------------------------------
#define LOADQ(IB, DST) {                                                      \
    const short* _qp = Qf +                                                   \
        ((((size_t)(b * 128 + (IB)) * 4) * 2 + hi) * 32 + l31) * 8;           \
    DST[0] = *reinterpret_cast<const s8b*>(_qp);                              \
    DST[1] = *reinterpret_cast<const s8b*>(_qp + 512);                        \
    DST[2] = *reinterpret_cast<const s8b*>(_qp + 1024);                       \
    DST[3] = *reinterpret_cast<const s8b*>(_qp + 1536); }

#define LOADV(IB, DST) {                                                      \
    const short* _vp = Vf +                                                   \
        ((((size_t)(b * 128 + (IB)) * 2) * 2 + hi) * 64 + l31) * 8;           \
    DST[0] = *reinterpret_cast<const s8b*>(_vp);                              \
    DST[1] = *reinterpret_cast<const s8b*>(_vp + 256);                        \
    DST[2] = *reinterpret_cast<const s8b*>(_vp + 1024);                       \
    DST[3] = *reinterpret_cast<const s8b*>(_vp + 1280); }

#define ABODY(QARR, VARR, IB) {                                               \
    f32x16 sacc;                                                              \
    _Pragma("unroll") for (int r = 0; r < 16; ++r) sacc[r] = 0.f;             \
    __builtin_amdgcn_s_setprio(1);                                            \
    _Pragma("unroll") for (int s = 0; s < 4; ++s)                             \
        sacc = __builtin_amdgcn_mfma_f32_32x32x16_bf16(QARR[s], kf[s], sacc, 0, 0, 0); \
    __builtin_amdgcn_s_setprio(0);                                            \
    float p[16];                                                              \
    const int _ibase = (IB) * 32 + 4 * hi;                                    \
    _Pragma("unroll") for (int g = 0; g < 4; ++g) {                           \
        f32x4 li = *reinterpret_cast<const f32x4*>(lip + _ibase + 8 * g);     \
        _Pragma("unroll") for (int q = 0; q < 4; ++q)                         \
            p[g * 4 + q] = __builtin_exp2f(sacc[g * 4 + q]) * li[q];          \
    }                                                                         \
    unsigned a0 = cvt_pk_bf16(p[0],  p[1]),  a1 = cvt_pk_bf16(p[2],  p[3]);   \
    unsigned a2 = cvt_pk_bf16(p[4],  p[5]),  a3 = cvt_pk_bf16(p[6],  p[7]);   \
    unsigned b0 = cvt_pk_bf16(p[8],  p[9]),  b1 = cvt_pk_bf16(p[10], p[11]);  \
    unsigned b2 = cvt_pk_bf16(p[12], p[13]), b3 = cvt_pk_bf16(p[14], p[15]);  \
    permswap(a0, a2); permswap(a1, a3); permswap(b0, b2); permswap(b1, b3);   \
    PackAB pa0, pa1;                                                          \
    pa0.u.x = a0; pa0.u.y = a1; pa0.u.z = a2; pa0.u.w = a3;                   \
    pa1.u.x = b0; pa1.u.y = b1; pa1.u.z = b2; pa1.u.w = b3;                   \
    __builtin_amdgcn_s_setprio(1);                                            \
    acc0 = __builtin_amdgcn_mfma_f32_32x32x16_bf16(pa0.s, VARR[0], acc0, 0, 0, 0); \
    acc1 = __builtin_amdgcn_mfma_f32_32x32x16_bf16(pa0.s, VARR[1], acc1, 0, 0, 0); \
    acc0 = __builtin_amdgcn_mfma_f32_32x32x16_bf16(pa1.s, VARR[2], acc0, 0, 0, 0); \
    acc1 = __builtin_amdgcn_mfma_f32_32x32x16_bf16(pa1.s, VARR[3], acc1, 0, 0, 0); \
    __builtin_amdgcn_s_setprio(0); }

__global__ __launch_bounds__(512, 2) void attnout_kernel(
    const short* __restrict__ Qf, const short* __restrict__ Kf,
    const short* __restrict__ Vf, const float* __restrict__ inv_l,
    const float* __restrict__ x, const float* __restrict__ go,
    const float* __restrict__ beo, float* __restrict__ out)
{
    __shared__ float red[2][3][64][33];    // [wc][wr-1][c][j]

    const int t = threadIdx.x;
    const int b = blockIdx.x & 7;
    const int jt = blockIdx.x >> 3;        // 0..63 -> j0 = jt*64
    const int wave = t >> 6, lane = t & 63;
    const int wr = wave >> 1;              // 0..3 i-split
    const int wc = wave & 1;               // j-half
    const int l31 = lane & 31, hi = lane >> 5;

    const short* kp = Kf +
        ((((size_t)(b * 128 + jt * 2 + wc) * 4) * 2 + hi) * 32 + l31) * 8;
    s8b kf[4];
#pragma unroll
    for (int s = 0; s < 4; ++s)
        kf[s] = *reinterpret_cast<const s8b*>(kp + s * 512);

    f32x16 acc0, acc1;
#pragma unroll
    for (int r = 0; r < 16; ++r) { acc0[r] = 0.f; acc1[r] = 0.f; }

    const float* lip = inv_l + (((size_t)b) << 12);

    s8b qA[4], qB[4], vA[4], vB[4];
    LOADQ(wr, qA);
    LOADV(wr, vA);
    for (int ii = 0; ii < 32; ii += 2) {
        const int ibA = ii * 4 + wr;
        const int ibB = ibA + 4;
        LOADQ(ibB, qB);
        LOADV(ibB, vB);
        ABODY(qA, vA, ibA);
        if (ii + 2 < 32) { LOADQ(ibA + 8, qA); LOADV(ibA + 8, vA); }
        ABODY(qB, vB, ibB);
    }

    if (wr > 0) {
#pragma unroll
        for (int nf = 0; nf < 2; ++nf) {
            const f32x16& A = nf ? acc1 : acc0;
            int c = nf * 32 + l31;
#pragma unroll
            for (int g = 0; g < 4; ++g) {
                f32x4 v;
                v.x = A[g * 4 + 0]; v.y = A[g * 4 + 1];
                v.z = A[g * 4 + 2]; v.w = A[g * 4 + 3];
                *reinterpret_cast<f32x4*>(&red[wc][wr - 1][c][g * 8 + 4 * hi]) = v;
            }
        }
    }
    __syncthreads();
    if (wr == 0) {
#pragma unroll
        for (int nf = 0; nf < 2; ++nf) {
            const f32x16& A = nf ? acc1 : acc0;
            int c = nf * 32 + l31;
            const float sc = go[c] * rsqrtf(1.0f + EPS);
            const float bb = beo[c];
            size_t rowb = (((size_t)(b * 64 + c)) << 12) + jt * 64 + wc * 32;
#pragma unroll
            for (int g = 0; g < 4; ++g) {
                int jl = g * 8 + 4 * hi;
                f32x4 p0 = *reinterpret_cast<const f32x4*>(&red[wc][0][c][jl]);
                f32x4 p1 = *reinterpret_cast<const f32x4*>(&red[wc][1][c][jl]);
                f32x4 p2 = *reinterpret_cast<const f32x4*>(&red[wc][2][c][jl]);
                f32x4 xv = *reinterpret_cast<const f32x4*>(x + rowb + jl);
                f32x4 ov;
                ov.x = (A[g * 4 + 0] + p0.x + p1.x + p2.x + xv.x) * sc + bb;
                ov.y = (A[g * 4 + 1] + p0.y + p1.y + p2.y + xv.y) * sc + bb;
                ov.z = (A[g * 4 + 2] + p0.z + p1.z + p2.z + xv.z) * sc + bb;
                ov.w = (A[g * 4 + 3] + p0.w + p1.w + p2.w + xv.w) * sc + bb;
                *reinterpret_cast<f32x4*>(out + rowb + jl) = ov;
            }
        }
    }
}

extern "C" void kernel_launch(void* const* d_in, const int* in_sizes, int n_in,
                              void* d_out, int out_size, void* d_ws, size_t ws_size,
                              hipStream_t stream)
{
    (void)in_sizes; (void)n_in; (void)out_size; (void)ws_size;
    const float* x   = (const float*)d_in[0];
    const float* sal = (const float*)d_in[1];
    const float* wq  = (const float*)d_in[2];  const float* bq  = (const float*)d_in[3];
    const float* gq  = (const float*)d_in[4];  const float* beq = (const float*)d_in[5];
    const float* wk  = (const float*)d_in[6];  const float* bk  = (const float*)d_in[7];
    const float* gk  = (const float*)d_in[8];  const float* bek = (const float*)d_in[9];
    const float* wv  = (const float*)d_in[10]; const float* bv  = (const float*)d_in[11];
    const float* gv  = (const float*)d_in[12]; const float* bev = (const float*)d_in[13];
    const float* go  = (const float*)d_in[14]; const float* beo = (const float*)d_in[15];
    float* out = (float*)d_out;

    short* ws = (short*)d_ws;
    short* Qf = ws;                     // 2,097,152 bf16
    short* Kf = ws + 2097152;           // 2,097,152 bf16
    short* Vf = ws + 4194304;           // 2,097,152 bf16
    float* il = (float*)(ws + 6291456); // 32,768 f32

    qkv_kernel<<<512, 256, 0, stream>>>(x, sal, wq, bq, gq, beq,
                                        wk, bk, gk, bek, wv, bv, gv, bev,
                                        Qf, Kf, Vf);
    rowsum_kernel<<<512, 512, 0, stream>>>(Qf, Kf, il);
    attnout_kernel<<<512, 512, 0, stream>>>(Qf, Kf, Vf, il, x, go, beo, out);
}

// Round 9
// 196.434 us; speedup vs baseline: 1.1333x; 1.0176x over previous
//
#include <hip/hip_runtime.h>

#define EPS 1e-5f
#define LOG2E 1.4426950408889634f

typedef __attribute__((ext_vector_type(8)))  short    s8b;    // 8 bf16 (4 VGPR)
typedef __attribute__((ext_vector_type(4)))  short    s4b;    // 4 bf16 (b64)
typedef __attribute__((ext_vector_type(16))) float    f32x16; // 32x32 MFMA acc
typedef __attribute__((ext_vector_type(4)))  float    f32x4;
typedef __attribute__((ext_vector_type(4)))  unsigned u32x4;

__device__ __forceinline__ unsigned cvt_pk_bf16(float lo, float hi) {
    unsigned r;
    asm("v_cvt_pk_bf16_f32 %0, %1, %2" : "=v"(r) : "v"(lo), "v"(hi));
    return r;
}
__device__ __forceinline__ void permswap(unsigned &a, unsigned &b) {
    asm("v_permlane32_swap_b32 %0, %1" : "+v"(a), "+v"(b));
}
union PackAB { u32x4 u; s8b s; };

__device__ __forceinline__ unsigned short f2bf(float f) {
    union { float f; unsigned u; } v; v.f = f;
    unsigned r = v.u + 0x7FFFu + ((v.u >> 16) & 1u);
    return (unsigned short)(r >> 16);
}
__device__ __forceinline__ float bf2f(unsigned short h) {
    union { unsigned u; float f; } v; v.u = ((unsigned)h) << 16;
    return v.f;
}

// Fragment-major layouts (element indices, bf16):
//  Qf/Kf: ((((b*128 + ib)*4 + s)*2 + hi)*32 + l)*8 + e   i/j = ib*32+l, k = s*16+hi*8+e
//  Vf:    ((((b*128 + ib)*2 + s2)*2 + hi)*64 + c)*8 + e  k=i = ib*32+s2*16+hi*8+e, col=c
// Q is pre-scaled by LOG2E so exp(S) == exp2(S').

// ---------------------------------------------------------------------------
// Kernel A (MFMA): fused 1x1-conv + BN (+ mask, +LOG2E for Q), bf16-split W
// block = (b, 64-wide p strip); 4 waves = phalf(2) x ohalf(2)
// ---------------------------------------------------------------------------
__global__ __launch_bounds__(256) void qkv_kernel(
    const float* __restrict__ x, const float* __restrict__ sal,
    const float* __restrict__ wq, const float* __restrict__ bq,
    const float* __restrict__ gq, const float* __restrict__ beq,
    const float* __restrict__ wk, const float* __restrict__ bk,
    const float* __restrict__ gk, const float* __restrict__ bek,
    const float* __restrict__ wv, const float* __restrict__ bv,
    const float* __restrict__ gv, const float* __restrict__ bev,
    short* __restrict__ Qf, short* __restrict__ Kf, short* __restrict__ Vf)
{
    __shared__ short wbf[6][4096];    // [m*2+hl][(o*64+c) ^ ((o&7)<<3)]
    __shared__ short xbf[4096];       // [(p*64+c) ^ ((p&7)<<3)]
    __shared__ short v_lds[4096];     // [(c*64+p) ^ ((c&7)<<3)]
    __shared__ float sc_lds[3][64];
    __shared__ float bb_lds[3][64];

    const int t = threadIdx.x;
    const int b = blockIdx.x & 7;
    const int p0 = (blockIdx.x >> 3) * 64;

    if (t < 192) {
        int m = t >> 6, o = t & 63;
        const float* g  = (m == 0) ? gq  : (m == 1) ? gk  : gv;
        const float* be = (m == 0) ? beq : (m == 1) ? bek : bev;
        const float* bi = (m == 0) ? bq  : (m == 1) ? bk  : bv;
        float lam = (m == 0) ? LOG2E : 1.0f;
        float s = g[o] * rsqrtf(1.0f + EPS) * lam;
        sc_lds[m][o] = s;
        bb_lds[m][o] = bi[o] * s + be[o] * lam;
    }
    __syncthreads();

    // stage W -> scaled bf16 hi/lo split
    for (int rep = 0; rep < 12; ++rep) {
        int idx = (rep * 256 + t) * 4;
        int m = idx >> 12;
        int r = idx & 4095;
        int o = r >> 6, c0 = r & 63;
        const float* w = (m == 0) ? wq : (m == 1) ? wk : wv;
        float4 v4 = *reinterpret_cast<const float4*>(w + r);
        float s = sc_lds[m][o];
        float w0 = v4.x * s, w1 = v4.y * s, w2 = v4.z * s, w3 = v4.w * s;
        unsigned short h0 = f2bf(w0), h1 = f2bf(w1), h2 = f2bf(w2), h3 = f2bf(w3);
        s4b hv, lv;
        hv[0] = (short)h0; hv[1] = (short)h1; hv[2] = (short)h2; hv[3] = (short)h3;
        lv[0] = (short)f2bf(w0 - bf2f(h0));
        lv[1] = (short)f2bf(w1 - bf2f(h1));
        lv[2] = (short)f2bf(w2 - bf2f(h2));
        lv[3] = (short)f2bf(w3 - bf2f(h3));
        int sidx = (o * 64 + c0) ^ ((o & 7) << 3);
        *reinterpret_cast<s4b*>(&wbf[m * 2 + 0][sidx]) = hv;
        *reinterpret_cast<s4b*>(&wbf[m * 2 + 1][sidx]) = lv;
    }
    // stage x -> bf16, transposed [p][c]
    {
        const int xp = t & 63;
        const int cgrp = (t >> 6) * 4;
        const float* xb = x + ((size_t)(b * 64) << 12) + p0 + xp;
        for (int rep = 0; rep < 4; ++rep) {
            int cb = cgrp + rep * 16;
            float x0 = xb[(size_t)(cb + 0) << 12];
            float x1 = xb[(size_t)(cb + 1) << 12];
            float x2 = xb[(size_t)(cb + 2) << 12];
            float x3 = xb[(size_t)(cb + 3) << 12];
            s4b pk;
            pk[0] = (short)f2bf(x0); pk[1] = (short)f2bf(x1);
            pk[2] = (short)f2bf(x2); pk[3] = (short)f2bf(x3);
            int sidx = (xp * 64 + cb) ^ ((xp & 7) << 3);
            *reinterpret_cast<s4b*>(&xbf[sidx]) = pk;
        }
    }
    __syncthreads();

    const int lane = t & 63, wave = t >> 6;
    const int l31 = lane & 31, hi = lane >> 5;
    const int phalf = wave & 1, ohalf = wave >> 1;
    const int prow = phalf * 32 + l31;
    const int orow = ohalf * 32 + l31;
    const int ib = (p0 >> 5) + phalf;
    const int swz = (l31 & 7) << 3;

    s8b bx[4];
#pragma unroll
    for (int s = 0; s < 4; ++s)
        bx[s] = *reinterpret_cast<const s8b*>(
            &xbf[(prow * 64 + s * 16 + hi * 8) ^ ((prow & 7) << 3)]);

    const float msk = sal[(((size_t)b) << 12) + p0 + prow];

#pragma unroll
    for (int m = 0; m < 3; ++m) {
        s8b ah[4], al[4];
#pragma unroll
        for (int s = 0; s < 4; ++s) {
            int sidx = (orow * 64 + s * 16 + hi * 8) ^ swz;
            ah[s] = *reinterpret_cast<const s8b*>(&wbf[m * 2 + 0][sidx]);
            al[s] = *reinterpret_cast<const s8b*>(&wbf[m * 2 + 1][sidx]);
        }
        f32x16 d;
#pragma unroll
        for (int r = 0; r < 16; ++r) d[r] = 0.f;
#pragma unroll
        for (int s = 0; s < 4; ++s)
            d = __builtin_amdgcn_mfma_f32_32x32x16_bf16(ah[s], bx[s], d, 0, 0, 0);
#pragma unroll
        for (int s = 0; s < 4; ++s)
            d = __builtin_amdgcn_mfma_f32_32x32x16_bf16(al[s], bx[s], d, 0, 0, 0);

        float pv[16];
#pragma unroll
        for (int g = 0; g < 4; ++g) {
            f32x4 bb = *reinterpret_cast<const f32x4*>(
                &bb_lds[m][ohalf * 32 + 8 * g + 4 * hi]);
#pragma unroll
            for (int q = 0; q < 4; ++q) pv[g * 4 + q] = d[g * 4 + q] + bb[q];
        }
        if (m == 0) {
#pragma unroll
            for (int r = 0; r < 16; ++r) pv[r] *= msk;
        }
        if (m < 2) {
            unsigned a0 = cvt_pk_bf16(pv[0],  pv[1]);
            unsigned a1 = cvt_pk_bf16(pv[2],  pv[3]);
            unsigned a2 = cvt_pk_bf16(pv[4],  pv[5]);
            unsigned a3 = cvt_pk_bf16(pv[6],  pv[7]);
            unsigned b0 = cvt_pk_bf16(pv[8],  pv[9]);
            unsigned b1 = cvt_pk_bf16(pv[10], pv[11]);
            unsigned b2 = cvt_pk_bf16(pv[12], pv[13]);
            unsigned b3 = cvt_pk_bf16(pv[14], pv[15]);
            permswap(a0, a2); permswap(a1, a3);
            permswap(b0, b2); permswap(b1, b3);
            PackAB pa0, pa1;
            pa0.u.x = a0; pa0.u.y = a1; pa0.u.z = a2; pa0.u.w = a3;
            pa1.u.x = b0; pa1.u.y = b1; pa1.u.z = b2; pa1.u.w = b3;
            short* dst = (m == 0) ? Qf : Kf;
            size_t base =
                ((((size_t)(b * 128 + ib) * 4 + ohalf * 2) * 2 + hi) * 32 + l31) * 8;
            *reinterpret_cast<u32x4*>(dst + base)       = pa0.u;
            *reinterpret_cast<u32x4*>(dst + base + 512) = pa1.u;  // s+1
        } else {
#pragma unroll
            for (int r = 0; r < 16; ++r) {
                int c = ohalf * 32 + (r & 3) + 8 * (r >> 2) + 4 * hi;
                int sidx = (c * 64 + prow) ^ ((c & 7) << 3);
                v_lds[sidx] = (short)f2bf(pv[r]);
            }
        }
    }
    __syncthreads();

    // cooperative Vf write (fragment-major, contiguous)
    const size_t vbase = (size_t)(b * 128 + (p0 >> 5)) * 2048;
#pragma unroll
    for (int r = 0; r < 2; ++r) {
        int f = r * 256 + t;
        int c = f & 63;
        int iL = ((f >> 6) & 7) * 8;
        int sidx = (c * 64 + iL) ^ ((c & 7) << 3);
        u32x4 val = *reinterpret_cast<const u32x4*>(&v_lds[sidx]);
        *reinterpret_cast<u32x4*>(Vf + vbase + (size_t)f * 8) = val;
    }
}

// ---------------------------------------------------------------------------
// Kernel B (MFMA): inv_l[b][i] = 1 / sum_j exp2(S'[i][j])
// block = (b, 32-row i-block); 4 waves j-split 4-way; kf double-buffered.
// NO setprio. R4 grid (1024 x 256, 4 blocks/CU).
// ---------------------------------------------------------------------------
#define LOADK(JB, DST) {                                                      \
    const short* _kp = Kf +                                                   \
        ((((size_t)(b * 128 + (JB)) * 4) * 2 + hi) * 32 + l31) * 8;           \
    DST[0] = *reinterpret_cast<const s8b*>(_kp);                              \
    DST[1] = *reinterpret_cast<const s8b*>(_kp + 512);                        \
    DST[2] = *reinterpret_cast<const s8b*>(_kp + 1024);                       \
    DST[3] = *reinterpret_cast<const s8b*>(_kp + 1536); }

#define RBODY(KARR) {                                                         \
    f32x16 sacc;                                                              \
    _Pragma("unroll") for (int r = 0; r < 16; ++r) sacc[r] = 0.f;             \
    _Pragma("unroll") for (int s = 0; s < 4; ++s)                             \
        sacc = __builtin_amdgcn_mfma_f32_32x32x16_bf16(qf[s], KARR[s], sacc, 0, 0, 0); \
    _Pragma("unroll") for (int r = 0; r < 16; ++r)                            \
        lsum[r] += __builtin_exp2f(sacc[r]); }

__global__ __launch_bounds__(256, 4) void rowsum_kernel(
    const short* __restrict__ Qf, const short* __restrict__ Kf,
    float* __restrict__ inv_l)
{
    __shared__ float part[4][32];

    const int t = threadIdx.x;
    const int b = blockIdx.x & 7;
    const int it = blockIdx.x >> 3;          // i-block 0..127
    const int wave = t >> 6, lane = t & 63;
    const int wj = wave;                     // j-split 0..3
    const int l31 = lane & 31, hi = lane >> 5;

    const short* qp = Qf +
        ((((size_t)(b * 128 + it) * 4) * 2 + hi) * 32 + l31) * 8;
    s8b qf[4];
#pragma unroll
    for (int s = 0; s < 4; ++s)
        qf[s] = *reinterpret_cast<const s8b*>(qp + s * 512);

    float lsum[16];
#pragma unroll
    for (int r = 0; r < 16; ++r) lsum[r] = 0.f;

    s8b kA[4], kB[4];
    LOADK(wj, kA);
    for (int jj = 0; jj < 32; jj += 2) {
        LOADK((jj + 1) * 4 + wj, kB);
        RBODY(kA);
        if (jj + 2 < 32) { LOADK((jj + 2) * 4 + wj, kA); }
        RBODY(kB);
    }

#pragma unroll
    for (int off = 1; off < 32; off <<= 1)
#pragma unroll
        for (int r = 0; r < 16; ++r) lsum[r] += __shfl_xor(lsum[r], off);

    if (l31 == 0) {
#pragma unroll
        for (int r = 0; r < 16; ++r) {
            int iloc = (r & 3) + 8 * (r >> 2) + 4 * hi;
            part[wave][iloc] = lsum[r];
        }
    }
    __syncthreads();
    if (t < 32)
        inv_l[(((size_t)b) << 12) + it * 32 + t] =
            1.0f / (part[0][t] + part[1][t] + part[2][t] + part[3][t]);
}

// ---------------------------------------------------------------------------
// Kernel C (MFMA): out = BN_o( V @ softmax + x )
// R4 structure verbatim (512 blocks, 512 thr, wr 4-way x wc 2-way,
// launch_bounds(512,4), no setprio, no explicit dbuf) + exp2.
// ---------------------------------------------------------------------------
__global__ __launch_bounds__(512, 4) void attnout_kernel(
    const short* __restrict__ Qf, const short* __restrict__ Kf,
    const short* __restrict__ Vf, const float* __restrict__ inv_l,
    const float* __restrict__ x, const float* __restrict__ go,
    const float* __restrict__ beo, float* __restrict__ out)
{
    __shared__ float red[2][3][64][33];   // [wc][wr-1][c][j]

    const int t = threadIdx.x;
    const int b = blockIdx.x & 7;
    const int jt = blockIdx.x >> 3;        // 0..63  -> j0 = jt*64
    const int wave = t >> 6, lane = t & 63;
    const int wr = wave >> 1;              // 0..3 i-split
    const int wc = wave & 1;               // j-half
    const int l31 = lane & 31, hi = lane >> 5;

    // K B-frags fixed: j-block = jt*2 + wc
    const short* kp = Kf +
        ((((size_t)(b * 128 + jt * 2 + wc) * 4) * 2 + hi) * 32 + l31) * 8;
    s8b kf[4];
#pragma unroll
    for (int s = 0; s < 4; ++s)
        kf[s] = *reinterpret_cast<const s8b*>(kp + s * 512);

    f32x16 acc0, acc1;
#pragma unroll
    for (int r = 0; r < 16; ++r) { acc0[r] = 0.f; acc1[r] = 0.f; }

    const float* lip = inv_l + (((size_t)b) << 12);

    for (int ii = 0; ii < 32; ++ii) {
        const int ib = ii * 4 + wr;        // i-block 0..127
        const short* qp = Qf +
            ((((size_t)(b * 128 + ib) * 4) * 2 + hi) * 32 + l31) * 8;
        s8b qf[4];
#pragma unroll
        for (int s = 0; s < 4; ++s)
            qf[s] = *reinterpret_cast<const s8b*>(qp + s * 512);

        const short* vp = Vf +
            ((((size_t)(b * 128 + ib) * 2) * 2 + hi) * 64 + l31) * 8;
        s8b vf[2][2];
#pragma unroll
        for (int s2 = 0; s2 < 2; ++s2)
#pragma unroll
            for (int nf = 0; nf < 2; ++nf)
                vf[s2][nf] = *reinterpret_cast<const s8b*>(
                    vp + s2 * 1024 + nf * 256);

        f32x4 li[4];
#pragma unroll
        for (int g = 0; g < 4; ++g)
            li[g] = *reinterpret_cast<const f32x4*>(lip + ib * 32 + 4 * hi + 8 * g);

        f32x16 sacc;
#pragma unroll
        for (int r = 0; r < 16; ++r) sacc[r] = 0.f;
#pragma unroll
        for (int s = 0; s < 4; ++s)
            sacc = __builtin_amdgcn_mfma_f32_32x32x16_bf16(qf[s], kf[s], sacc, 0, 0, 0);

        float p[16];
#pragma unroll
        for (int g = 0; g < 4; ++g)
#pragma unroll
            for (int q = 0; q < 4; ++q)
                p[g * 4 + q] = __builtin_exp2f(sacc[g * 4 + q]) * li[g][q];

        unsigned a0 = cvt_pk_bf16(p[0],  p[1]);
        unsigned a1 = cvt_pk_bf16(p[2],  p[3]);
        unsigned a2 = cvt_pk_bf16(p[4],  p[5]);
        unsigned a3 = cvt_pk_bf16(p[6],  p[7]);
        unsigned b0 = cvt_pk_bf16(p[8],  p[9]);
        unsigned b1 = cvt_pk_bf16(p[10], p[11]);
        unsigned b2 = cvt_pk_bf16(p[12], p[13]);
        unsigned b3 = cvt_pk_bf16(p[14], p[15]);
        permswap(a0, a2); permswap(a1, a3);
        permswap(b0, b2); permswap(b1, b3);
        PackAB pa0, pa1;
        pa0.u.x = a0; pa0.u.y = a1; pa0.u.z = a2; pa0.u.w = a3;
        pa1.u.x = b0; pa1.u.y = b1; pa1.u.z = b2; pa1.u.w = b3;

        acc0 = __builtin_amdgcn_mfma_f32_32x32x16_bf16(pa0.s, vf[0][0], acc0, 0, 0, 0);
        acc1 = __builtin_amdgcn_mfma_f32_32x32x16_bf16(pa0.s, vf[0][1], acc1, 0, 0, 0);
        acc0 = __builtin_amdgcn_mfma_f32_32x32x16_bf16(pa1.s, vf[1][0], acc0, 0, 0, 0);
        acc1 = __builtin_amdgcn_mfma_f32_32x32x16_bf16(pa1.s, vf[1][1], acc1, 0, 0, 0);
    }

    // tree combine across wr
    if (wr > 0) {
#pragma unroll
        for (int nf = 0; nf < 2; ++nf) {
            const f32x16& A = nf ? acc1 : acc0;
            int c = nf * 32 + l31;
#pragma unroll
            for (int g = 0; g < 4; ++g) {
                f32x4 v;
                v.x = A[g * 4 + 0]; v.y = A[g * 4 + 1];
                v.z = A[g * 4 + 2]; v.w = A[g * 4 + 3];
                *reinterpret_cast<f32x4*>(&red[wc][wr - 1][c][g * 8 + 4 * hi]) = v;
            }
        }
    }
    __syncthreads();
    if (wr == 0) {
#pragma unroll
        for (int nf = 0; nf < 2; ++nf) {
            const f32x16& A = nf ? acc1 : acc0;
            int c = nf * 32 + l31;
            const float sc = go[c] * rsqrtf(1.0f + EPS);
            const float bb = beo[c];
            size_t rowb = (((size_t)(b * 64 + c)) << 12) + jt * 64 + wc * 32;
#pragma unroll
            for (int g = 0; g < 4; ++g) {
                int jl = g * 8 + 4 * hi;
                f32x4 p0 = *reinterpret_cast<const f32x4*>(&red[wc][0][c][jl]);
                f32x4 p1 = *reinterpret_cast<const f32x4*>(&red[wc][1][c][jl]);
                f32x4 p2 = *reinterpret_cast<const f32x4*>(&red[wc][2][c][jl]);
                f32x4 xv = *reinterpret_cast<const f32x4*>(x + rowb + jl);
                f32x4 ov;
                ov.x = (A[g * 4 + 0] + p0.x + p1.x + p2.x + xv.x) * sc + bb;
                ov.y = (A[g * 4 + 1] + p0.y + p1.y + p2.y + xv.y) * sc + bb;
                ov.z = (A[g * 4 + 2] + p0.z + p1.z + p2.z + xv.z) * sc + bb;
                ov.w = (A[g * 4 + 3] + p0.w + p1.w + p2.w + xv.w) * sc + bb;
                *reinterpret_cast<f32x4*>(out + rowb + jl) = ov;
            }
        }
    }
}

extern "C" void kernel_launch(void* const* d_in, const int* in_sizes, int n_in,
                              void* d_out, int out_size, void* d_ws, size_t ws_size,
                              hipStream_t stream)
{
    (void)in_sizes; (void)n_in; (void)out_size; (void)ws_size;
    const float* x   = (const float*)d_in[0];
    const float* sal = (const float*)d_in[1];
    const float* wq  = (const float*)d_in[2];  const float* bq  = (const float*)d_in[3];
    const float* gq  = (const float*)d_in[4];  const float* beq = (const float*)d_in[5];
    const float* wk  = (const float*)d_in[6];  const float* bk  = (const float*)d_in[7];
    const float* gk  = (const float*)d_in[8];  const float* bek = (const float*)d_in[9];
    const float* wv  = (const float*)d_in[10]; const float* bv  = (const float*)d_in[11];
    const float* gv  = (const float*)d_in[12]; const float* bev = (const float*)d_in[13];
    const float* go  = (const float*)d_in[14]; const float* beo = (const float*)d_in[15];
    float* out = (float*)d_out;

    short* ws = (short*)d_ws;
    short* Qf = ws;                     // 2,097,152 bf16
    short* Kf = ws + 2097152;           // 2,097,152 bf16
    short* Vf = ws + 4194304;           // 2,097,152 bf16
    float* il = (float*)(ws + 6291456); // 32,768 f32

    qkv_kernel<<<512, 256, 0, stream>>>(x, sal, wq, bq, gq, beq,
                                        wk, bk, gk, bek, wv, bv, gv, bev,
                                        Qf, Kf, Vf);
    rowsum_kernel<<<1024, 256, 0, stream>>>(Qf, Kf, il);
    attnout_kernel<<<512, 512, 0, stream>>>(Qf, Kf, Vf, il, x, go, beo, out);
}